// Round 1
// 1293.453 us; speedup vs baseline: 1.0125x; 1.0125x over previous
//
#include <hip/hip_runtime.h>
#include <stdint.h>

// MoE top-2 SwiGLU FFN, MI355X. fp32 in/out, bf16 MFMA compute.
// B=4 S=2048 H=1024 F=4096 E=8 K=2 -> T=8192 tokens, 16384 pairs.
// R3: gemm1/gemm2 rebuilt as phase-interleaved 3-deep LDS pipelines
//     (T3+T4 counted vmcnt, T2 XOR-swizzle via pre-swizzled global src,
//     T5 setprio MFMA clusters). 512 thr / 8 waves, BK=64, dynamic LDS.

#define Hdim 1024
#define Fdim 4096
#define NE 8
#define NT 8192
#define NPAIR 16384
#define OUT0 (NT * Hdim)   // 8388608 floats, then router_logits [NT,8]

typedef unsigned short u16;
typedef __bf16 bf16x8 __attribute__((ext_vector_type(8)));
typedef unsigned short u16x8 __attribute__((ext_vector_type(8)));
typedef float f32x4 __attribute__((ext_vector_type(4)));

// ---- workspace layout (bytes) ----
#define WS_HDR      0ull
#define WS_TOKTOP   4096ull
#define WS_TOKW     69632ull
#define WS_ROWTOK   135168ull
#define WS_ROWW     200704ull
#define WS_XG       266240ull          // bf16 [16384][1024]
#define WS_WG       33820672ull        // packed bf16 [8][32][32][128][32]
#define WS_WU       100929536ull
#define WS_WD       168038400ull       // packed bf16 [8][8][128][128][32]
#define WS_ACT      235147264ull       // bf16 [16384][4096]
#define WS_NEEDED   369364992ull

// hdr int indices
#define HDR_CNT 0
#define HDR_OFF 8
#define HDR_CUR 16
#define HDR_TOTALM 24
#define HDR_BEXP 32      // 160 slots
#define HDR_BSTART 192
#define HDR_BCNT 352

__device__ __forceinline__ u16 f2bf(float f) {
  union { float f; unsigned int u; } v; v.f = f;
  unsigned int u = v.u;
  u += 0x7fffu + ((u >> 16) & 1u);   // round-to-nearest-even
  return (u16)(u >> 16);
}

// async global->LDS, 16B per lane. lds base must be wave-uniform; HW adds lane*16.
__device__ __forceinline__ void gl2lds16(const void* g, void* l) {
  __builtin_amdgcn_global_load_lds(
      (__attribute__((address_space(1))) void*)(uintptr_t)g,
      (__attribute__((address_space(3))) void*)(uint32_t)(uintptr_t)l,
      16, 0, 0);
}

__global__ void k_sentinel(float* out) { out[0] = 3.0e8f; }

// ---- pack: fp32 [K][N] -> bf16 tiles [nb][kb][128][32], contiguous 8KB each ----
__global__ void k_pack(const float* __restrict__ wgp, const float* __restrict__ wup,
                       const float* __restrict__ wdp, u16* __restrict__ PG,
                       u16* __restrict__ PU, u16* __restrict__ PD) {
  __shared__ float lds[32 * 129];
  int tile = blockIdx.x;
  int tensor = tile >> 13;     // 8192 tiles per tensor
  int rem = tile & 8191;
  const float* src; u16* dst; int rowStride;
  int e = rem >> 10, r2 = rem & 1023;
  if (tensor == 0) {
    int nb = r2 >> 5, kb = r2 & 31;
    src = wgp + ((size_t)e * 1024 + kb * 32) * 4096 + nb * 128;
    rowStride = 4096; dst = PG + (size_t)rem * 4096;
  } else if (tensor == 1) {
    int nb = r2 >> 5, kb = r2 & 31;
    src = wup + ((size_t)e * 1024 + kb * 32) * 4096 + nb * 128;
    rowStride = 4096; dst = PU + (size_t)rem * 4096;
  } else {
    int nb = r2 >> 7, kb = r2 & 127;
    src = wdp + ((size_t)e * 4096 + kb * 32) * 1024 + nb * 128;
    rowStride = 1024; dst = PD + (size_t)rem * 4096;
  }
  int tid = threadIdx.x;
  for (int h = 0; h < 4; ++h) {
    int c = tid + h * 256;          // 1024 float4 chunks
    int k = c >> 5, n = (c & 31) * 4;
    f32x4 v = *(const f32x4*)(src + (size_t)k * rowStride + n);
    lds[k * 129 + n + 0] = v[0];
    lds[k * 129 + n + 1] = v[1];
    lds[k * 129 + n + 2] = v[2];
    lds[k * 129 + n + 3] = v[3];
  }
  __syncthreads();
  for (int h = 0; h < 2; ++h) {
    int c = tid + h * 256;          // 512 16B chunks of dst
    int ni = c >> 2, ki0 = (c & 3) * 8;
    u16x8 o;
#pragma unroll
    for (int j = 0; j < 8; ++j) o[j] = f2bf(lds[(ki0 + j) * 129 + ni]);
    *(u16x8*)(dst + c * 8) = o;
  }
}

// ---- router: logits, softmax, top-2, counts ----
__global__ void k_router(const float* __restrict__ x, const float* __restrict__ wg,
                         float* __restrict__ logits, int* __restrict__ hdr,
                         int* __restrict__ tokTop, float* __restrict__ tokW) {
  int t = blockIdx.x;
  int lane = threadIdx.x;   // 64 threads
  float acc[NE] = {0.f, 0.f, 0.f, 0.f, 0.f, 0.f, 0.f, 0.f};
  const float* xr = x + (size_t)t * Hdim + lane * 16;
#pragma unroll
  for (int j4 = 0; j4 < 4; ++j4) {
    f32x4 xv = *(const f32x4*)(xr + j4 * 4);
    int k0 = lane * 16 + j4 * 4;
#pragma unroll
    for (int kk = 0; kk < 4; ++kk) {
      f32x4 w0 = *(const f32x4*)(wg + (size_t)(k0 + kk) * 8);
      f32x4 w1 = *(const f32x4*)(wg + (size_t)(k0 + kk) * 8 + 4);
      float xs = xv[kk];
      acc[0] += xs * w0[0]; acc[1] += xs * w0[1]; acc[2] += xs * w0[2]; acc[3] += xs * w0[3];
      acc[4] += xs * w1[0]; acc[5] += xs * w1[1]; acc[6] += xs * w1[2]; acc[7] += xs * w1[3];
    }
  }
#pragma unroll
  for (int off = 32; off > 0; off >>= 1)
#pragma unroll
    for (int e = 0; e < NE; ++e) acc[e] += __shfl_xor(acc[e], off, 64);
  if (lane < NE) logits[(size_t)t * NE + lane] = acc[lane];
  if (lane == 0) {
    float m = acc[0];
#pragma unroll
    for (int e = 1; e < NE; ++e) m = fmaxf(m, acc[e]);
    float p[NE];
#pragma unroll
    for (int e = 0; e < NE; ++e) p[e] = expf(acc[e] - m);
    int i1 = 0; float p1 = p[0];
#pragma unroll
    for (int e = 1; e < NE; ++e) if (p[e] > p1) { p1 = p[e]; i1 = e; }
    int i2 = -1; float p2 = -1.f;
#pragma unroll
    for (int e = 0; e < NE; ++e) if (e != i1 && p[e] > p2) { p2 = p[e]; i2 = e; }
    float s = p1 + p2;
    tokTop[t * 2] = i1; tokTop[t * 2 + 1] = i2;
    tokW[t * 2] = p1 / s; tokW[t * 2 + 1] = p2 / s;
    atomicAdd(&hdr[HDR_CNT + i1], 1);
    atomicAdd(&hdr[HDR_CNT + i2], 1);
  }
}

// ---- scan: expert offsets + M-block map (<=136 blocks) ----
__global__ void k_scan(int* hdr) {
  if (threadIdx.x != 0 || blockIdx.x != 0) return;
  int cum = 0, mb = 0;
  for (int e = 0; e < NE; ++e) {
    hdr[HDR_OFF + e] = cum;
    int c = hdr[HDR_CNT + e];
    int nb = (c + 127) >> 7;
    for (int b = 0; b < nb; ++b) {
      hdr[HDR_BEXP + mb] = e;
      hdr[HDR_BSTART + mb] = cum + b * 128;
      int rc = c - b * 128; if (rc > 128) rc = 128;
      hdr[HDR_BCNT + mb] = rc;
      ++mb;
    }
    cum += c;
  }
  hdr[HDR_TOTALM] = mb;
}

// ---- place pairs into compact per-expert segments ----
__global__ void k_place(int* __restrict__ hdr, const int* __restrict__ tokTop,
                        const float* __restrict__ tokW, int* __restrict__ rowTok,
                        float* __restrict__ rowW) {
  int t = blockIdx.x * 256 + threadIdx.x;
  if (t >= NT) return;
#pragma unroll
  for (int k = 0; k < 2; ++k) {
    int e = tokTop[t * 2 + k];
    int pos = hdr[HDR_OFF + e] + atomicAdd(&hdr[HDR_CUR + e], 1);
    rowTok[pos] = t;
    rowW[pos] = tokW[t * 2 + k];
  }
}

// ---- gather x rows -> bf16 xg[pair][1024] ----
__global__ void k_gather(const float* __restrict__ x, const int* __restrict__ rowTok,
                         u16* __restrict__ xg) {
  int wid = threadIdx.x >> 6, lane = threadIdx.x & 63;
  int p = blockIdx.x * 4 + wid;
  int tok = rowTok[p];
  const float* src = x + (size_t)tok * Hdim;
  u16* dst = xg + (size_t)p * Hdim;
#pragma unroll
  for (int it = 0; it < 2; ++it) {
    int b = it * 512 + lane * 8;
    f32x4 a = *(const f32x4*)(src + b);
    f32x4 c = *(const f32x4*)(src + b + 4);
    u16x8 o;
    o[0] = f2bf(a[0]); o[1] = f2bf(a[1]); o[2] = f2bf(a[2]); o[3] = f2bf(a[3]);
    o[4] = f2bf(c[0]); o[5] = f2bf(c[1]); o[6] = f2bf(c[2]); o[7] = f2bf(c[3]);
    *(u16x8*)(dst + b) = o;
  }
}

// ---- GEMM1: [rows,1024]x[1024,128] dual (gate & up), fused SiLU*up -> act bf16 ----
// 512 thr / 8 waves (2M x 4N), block tile 128(M) x 128(F-cols) dual, BK=64.
// 3-deep LDS pipeline (stage t+2 while computing t), counted vmcnt(6),
// XOR-swizzled LDS (linear dest + pre-swizzled global src, rule 21),
// 2 phases/K-tile of 16 MFMA each with setprio.
// LDS buf (48KB): A[128][64]@0, BG[2kb][128][32]@16384, BU@32768. 3 bufs = 144KB.
__global__ __launch_bounds__(512, 1) void k_gemm1(
    const u16* __restrict__ xg, const u16* __restrict__ PG, const u16* __restrict__ PU,
    const int* __restrict__ hdr, u16* __restrict__ act) {
  extern __shared__ char ldsDyn[];
  int m = blockIdx.y;
  if (m >= hdr[HDR_TOTALM]) return;
  int e = hdr[HDR_BEXP + m], rowStart = hdr[HDR_BSTART + m], rowCnt = hdr[HDR_BCNT + m];
  int nb = blockIdx.x;                       // 0..31 over F in 128-col tiles
  int tid = threadIdx.x, lane = tid & 63, wid = tid >> 6;
  int wm = (wid & 1) * 64, wn = (wid >> 1) * 32;
  int rA = lane & 15, q = lane >> 4;

  // staging sources: per-lane PRE-SWIZZLED global addr; LDS dest stays linear.
  // A swizzle: within a 128B row, slot s holds logical kbytes (s^(row&7))*16.
  int arow = tid >> 3, aslot = tid & 7;
  int asw = (aslot ^ (arow & 7)) * 8;        // bf16 elems
  int pa0 = rowStart + arow;      if (pa0 > NPAIR - 1) pa0 = NPAIR - 1;
  int pa1 = rowStart + 64 + arow; if (pa1 > NPAIR - 1) pa1 = NPAIR - 1;
  const u16* sA0 = xg + (size_t)pa0 * 1024 + asw;
  const u16* sA1 = xg + (size_t)pa1 * 1024 + asw;
  // B swizzle: within a 64B row, slot s holds logical kbytes (s^(row&3))*16.
  int brow = tid >> 2, bslot = tid & 3;
  int bsw = (bslot ^ (brow & 3)) * 8;
  size_t tb = (size_t)(e * 1024 + nb * 32) * 4096 + (size_t)brow * 32 + bsw;
  const u16* sG = PG + tb;
  const u16* sU = PU + tb;

  // LDS read byte offsets (same XOR on read side)
  int arb[4], akx[2], brb[2];
#pragma unroll
  for (int i = 0; i < 4; ++i) arb[i] = (wm + i * 16 + rA) * 128;
  akx[0] = (q * 16) ^ ((rA & 7) << 4);
  akx[1] = (64 + q * 16) ^ ((rA & 7) << 4);
#pragma unroll
  for (int j = 0; j < 2; ++j) brb[j] = (wn + j * 16 + rA) * 64;
  int bkx = (q * 16) ^ ((rA & 3) << 4);

  f32x4 ag[4][2] = {};
  f32x4 au[4][2] = {};

  auto stageA = [&](int tt, char* sb) {     // A both halves + BG chunk0 (3 loads)
    gl2lds16(sA0 + tt * 64, sb + wid * 1024);
    gl2lds16(sA1 + tt * 64, sb + 8192 + wid * 1024);
    gl2lds16(sG + (size_t)tt * 8192, sb + 16384 + wid * 1024);
  };
  auto stageB = [&](int tt, char* sb) {     // BG chunk1 + BU both chunks (3 loads)
    gl2lds16(sG + (size_t)tt * 8192 + 4096, sb + 24576 + wid * 1024);
    gl2lds16(sU + (size_t)tt * 8192, sb + 32768 + wid * 1024);
    gl2lds16(sU + (size_t)tt * 8192 + 4096, sb + 40960 + wid * 1024);
  };

  stageA(0, ldsDyn); stageB(0, ldsDyn);
  stageA(1, ldsDyn + 49152); stageB(1, ldsDyn + 49152);

  int c = 0;
  for (int t = 0; t < 16; ++t) {
    // counted vmcnt: tile t complete, tile t+1's 6 loads stay in flight
    if (t < 15) asm volatile("s_waitcnt vmcnt(6)" ::: "memory");
    else        asm volatile("s_waitcnt vmcnt(0)" ::: "memory");
    __builtin_amdgcn_s_barrier();
    asm volatile("" ::: "memory");
    const char* bc = ldsDyn + c * 49152;
    int s = c + 2; if (s >= 3) s -= 3;
    char* sb = ldsDyn + s * 49152;
    // ---- phase A: A-frags i=0,1 + all B-frags; stage first half of tile t+2 ----
    bf16x8 a[2][2], g[2][2], u[2][2];
#pragma unroll
    for (int i = 0; i < 2; ++i)
#pragma unroll
      for (int kk = 0; kk < 2; ++kk)
        a[i][kk] = __builtin_bit_cast(bf16x8, *(const u16x8*)(bc + arb[i] + akx[kk]));
#pragma unroll
    for (int j = 0; j < 2; ++j)
#pragma unroll
      for (int kk = 0; kk < 2; ++kk) {
        g[j][kk] = __builtin_bit_cast(bf16x8, *(const u16x8*)(bc + 16384 + kk * 8192 + brb[j] + bkx));
        u[j][kk] = __builtin_bit_cast(bf16x8, *(const u16x8*)(bc + 32768 + kk * 8192 + brb[j] + bkx));
      }
    if (t < 14) stageA(t + 2, sb);
    asm volatile("" ::: "memory");
    __builtin_amdgcn_s_barrier();
    asm volatile("" ::: "memory");
    __builtin_amdgcn_s_setprio(1);
#pragma unroll
    for (int i = 0; i < 2; ++i)
#pragma unroll
      for (int j = 0; j < 2; ++j) {
        ag[i][j] = __builtin_amdgcn_mfma_f32_16x16x32_bf16(a[i][0], g[j][0], ag[i][j], 0, 0, 0);
        au[i][j] = __builtin_amdgcn_mfma_f32_16x16x32_bf16(a[i][0], u[j][0], au[i][j], 0, 0, 0);
        ag[i][j] = __builtin_amdgcn_mfma_f32_16x16x32_bf16(a[i][1], g[j][1], ag[i][j], 0, 0, 0);
        au[i][j] = __builtin_amdgcn_mfma_f32_16x16x32_bf16(a[i][1], u[j][1], au[i][j], 0, 0, 0);
      }
    __builtin_amdgcn_s_setprio(0);
    // ---- phase B: A-frags i=2,3; stage second half of tile t+2 ----
    bf16x8 a2[2][2];
#pragma unroll
    for (int i = 0; i < 2; ++i)
#pragma unroll
      for (int kk = 0; kk < 2; ++kk)
        a2[i][kk] = __builtin_bit_cast(bf16x8, *(const u16x8*)(bc + arb[2 + i] + akx[kk]));
    if (t < 14) stageB(t + 2, sb);
    asm volatile("" ::: "memory");
    __builtin_amdgcn_s_barrier();
    asm volatile("" ::: "memory");
    __builtin_amdgcn_s_setprio(1);
#pragma unroll
    for (int i = 0; i < 2; ++i)
#pragma unroll
      for (int j = 0; j < 2; ++j) {
        ag[2 + i][j] = __builtin_amdgcn_mfma_f32_16x16x32_bf16(a2[i][0], g[j][0], ag[2 + i][j], 0, 0, 0);
        au[2 + i][j] = __builtin_amdgcn_mfma_f32_16x16x32_bf16(a2[i][0], u[j][0], au[2 + i][j], 0, 0, 0);
        ag[2 + i][j] = __builtin_amdgcn_mfma_f32_16x16x32_bf16(a2[i][1], g[j][1], ag[2 + i][j], 0, 0, 0);
        au[2 + i][j] = __builtin_amdgcn_mfma_f32_16x16x32_bf16(a2[i][1], u[j][1], au[2 + i][j], 0, 0, 0);
      }
    __builtin_amdgcn_s_setprio(0);
    ++c; if (c == 3) c = 0;
  }
  // epilogue: h = silu(g)*u -> bf16 act[pair][F]
#pragma unroll
  for (int i = 0; i < 4; ++i)
#pragma unroll
    for (int r = 0; r < 4; ++r) {
      int row = wm + i * 16 + q * 4 + r;
      if (row < rowCnt) {
        size_t base = (size_t)(rowStart + row) * 4096 + nb * 128 + wn;
#pragma unroll
        for (int j = 0; j < 2; ++j) {
          float gv = ag[i][j][r], uv = au[i][j][r];
          float hv = (gv / (1.f + expf(-gv))) * uv;
          act[base + j * 16 + rA] = f2bf(hv);
        }
      }
    }
}

// ---- GEMM2: [rows,4096]x[4096,128] -> weighted atomic scatter into out ----
// Same pipeline: 512 thr / 8 waves, 128x128 tile, BK=64, 64 K-tiles,
// 3-deep LDS (32KB/buf = 96KB), counted vmcnt(4), 1 phase of 16 MFMA per tile.
__global__ __launch_bounds__(512, 1) void k_gemm2(
    const u16* __restrict__ act, const u16* __restrict__ PD,
    const int* __restrict__ hdr, const int* __restrict__ rowTok,
    const float* __restrict__ rowW, float* __restrict__ out) {
  extern __shared__ char ldsDyn[];
  int m = blockIdx.y;
  if (m >= hdr[HDR_TOTALM]) return;
  int e = hdr[HDR_BEXP + m], rowStart = hdr[HDR_BSTART + m], rowCnt = hdr[HDR_BCNT + m];
  int nb = blockIdx.x;                      // 0..7 over H in 128-col tiles
  int tid = threadIdx.x, lane = tid & 63, wid = tid >> 6;
  int wm = (wid & 1) * 64, wn = (wid >> 1) * 32;
  int rA = lane & 15, q = lane >> 4;

  int arow = tid >> 3, aslot = tid & 7;
  int asw = (aslot ^ (arow & 7)) * 8;
  int pa0 = rowStart + arow;      if (pa0 > NPAIR - 1) pa0 = NPAIR - 1;
  int pa1 = rowStart + 64 + arow; if (pa1 > NPAIR - 1) pa1 = NPAIR - 1;
  const u16* sA0 = act + (size_t)pa0 * 4096 + asw;
  const u16* sA1 = act + (size_t)pa1 * 4096 + asw;
  int brow = tid >> 2, bslot = tid & 3;
  int bsw = (bslot ^ (brow & 3)) * 8;
  const u16* sD = PD + ((size_t)(e * 8 + nb) * 128) * 4096 + (size_t)brow * 32 + bsw;

  int arb[4], akx[2], brb[2];
#pragma unroll
  for (int i = 0; i < 4; ++i) arb[i] = (wm + i * 16 + rA) * 128;
  akx[0] = (q * 16) ^ ((rA & 7) << 4);
  akx[1] = (64 + q * 16) ^ ((rA & 7) << 4);
#pragma unroll
  for (int j = 0; j < 2; ++j) brb[j] = (wn + j * 16 + rA) * 64;
  int bkx = (q * 16) ^ ((rA & 3) << 4);

  f32x4 acc[4][2] = {};
  auto stg = [&](int tt, char* sb) {        // 4 loads: A both halves, B both chunks
    gl2lds16(sA0 + tt * 64, sb + wid * 1024);
    gl2lds16(sA1 + tt * 64, sb + 8192 + wid * 1024);
    gl2lds16(sD + (size_t)tt * 8192, sb + 16384 + wid * 1024);
    gl2lds16(sD + (size_t)tt * 8192 + 4096, sb + 24576 + wid * 1024);
  };
  stg(0, ldsDyn); stg(1, ldsDyn + 32768);
  int c = 0;
  for (int t = 0; t < 64; ++t) {
    if (t < 63) asm volatile("s_waitcnt vmcnt(4)" ::: "memory");
    else        asm volatile("s_waitcnt vmcnt(0)" ::: "memory");
    __builtin_amdgcn_s_barrier();
    asm volatile("" ::: "memory");
    const char* bc = ldsDyn + c * 32768;
    int s = c + 2; if (s >= 3) s -= 3;
    bf16x8 a[4][2], b[2][2];
#pragma unroll
    for (int i = 0; i < 4; ++i)
#pragma unroll
      for (int kk = 0; kk < 2; ++kk)
        a[i][kk] = __builtin_bit_cast(bf16x8, *(const u16x8*)(bc + arb[i] + akx[kk]));
#pragma unroll
    for (int j = 0; j < 2; ++j)
#pragma unroll
      for (int kk = 0; kk < 2; ++kk)
        b[j][kk] = __builtin_bit_cast(bf16x8, *(const u16x8*)(bc + 16384 + kk * 8192 + brb[j] + bkx));
    if (t < 62) stg(t + 2, ldsDyn + s * 32768);
    asm volatile("" ::: "memory");
    __builtin_amdgcn_s_barrier();
    asm volatile("" ::: "memory");
    __builtin_amdgcn_s_setprio(1);
#pragma unroll
    for (int i = 0; i < 4; ++i)
#pragma unroll
      for (int j = 0; j < 2; ++j) {
        acc[i][j] = __builtin_amdgcn_mfma_f32_16x16x32_bf16(a[i][0], b[j][0], acc[i][j], 0, 0, 0);
        acc[i][j] = __builtin_amdgcn_mfma_f32_16x16x32_bf16(a[i][1], b[j][1], acc[i][j], 0, 0, 0);
      }
    __builtin_amdgcn_s_setprio(0);
    ++c; if (c == 3) c = 0;
  }
#pragma unroll
  for (int i = 0; i < 4; ++i)
#pragma unroll
    for (int r = 0; r < 4; ++r) {
      int row = wm + i * 16 + q * 4 + r;
      if (row < rowCnt) {
        int p = rowStart + row;
        int tok = rowTok[p];
        float w = rowW[p];
        size_t base = (size_t)tok * Hdim + nb * 128 + wn;
#pragma unroll
        for (int j = 0; j < 2; ++j)
          atomicAdd(&out[base + j * 16 + rA], w * acc[i][j][r]);
      }
    }
}

extern "C" void kernel_launch(void* const* d_in, const int* in_sizes, int n_in,
                              void* d_out, int out_size, void* d_ws, size_t ws_size,
                              hipStream_t stream) {
  const float* x   = (const float*)d_in[0];
  const float* wg  = (const float*)d_in[1];
  const float* wgp = (const float*)d_in[2];
  const float* wup = (const float*)d_in[3];
  const float* wdp = (const float*)d_in[4];
  float* out = (float*)d_out;

  if (ws_size < WS_NEEDED) { k_sentinel<<<1, 1, 0, stream>>>(out); return; }

  static int attrDone = 0;
  if (!attrDone) {
    hipFuncSetAttribute((const void*)k_gemm1,
                        hipFuncAttributeMaxDynamicSharedMemorySize, 147456);
    hipFuncSetAttribute((const void*)k_gemm2,
                        hipFuncAttributeMaxDynamicSharedMemorySize, 98304);
    attrDone = 1;
  }

  char* ws = (char*)d_ws;
  int*   hdr    = (int*)(ws + WS_HDR);
  int*   tokTop = (int*)(ws + WS_TOKTOP);
  float* tokW   = (float*)(ws + WS_TOKW);
  int*   rowTok = (int*)(ws + WS_ROWTOK);
  float* rowW   = (float*)(ws + WS_ROWW);
  u16*   xg     = (u16*)(ws + WS_XG);
  u16*   PG     = (u16*)(ws + WS_WG);
  u16*   PU     = (u16*)(ws + WS_WU);
  u16*   PD     = (u16*)(ws + WS_WD);
  u16*   act    = (u16*)(ws + WS_ACT);

  hipMemsetAsync(hdr, 0, 4096, stream);
  hipMemsetAsync(out, 0, (size_t)OUT0 * sizeof(float), stream);

  k_pack<<<24576, 256, 0, stream>>>(wgp, wup, wdp, PG, PU, PD);
  k_router<<<NT, 64, 0, stream>>>(x, wg, out + OUT0, hdr, tokTop, tokW);
  k_scan<<<1, 1, 0, stream>>>(hdr);
  k_place<<<32, 256, 0, stream>>>(hdr, tokTop, tokW, rowTok, rowW);
  k_gather<<<4096, 256, 0, stream>>>(x, rowTok, xg);
  k_gemm1<<<dim3(32, 136), 512, 147456, stream>>>(xg, PG, PU, hdr, act);
  k_gemm2<<<dim3(8, 136), 512, 98304, stream>>>(act, PD, hdr, rowTok, rowW, out);
}

// Round 3
// 1275.436 us; speedup vs baseline: 1.0268x; 1.0141x over previous
//
#include <hip/hip_runtime.h>
#include <stdint.h>

// MoE top-2 SwiGLU FFN, MI355X. fp32 in/out, bf16 MFMA compute.
// B=4 S=2048 H=1024 F=4096 E=8 K=2 -> T=8192 tokens, 16384 pairs.
// R4 (resubmit; prior run died to container infra failure):
//     4-wave blocks, 2 blocks/CU (implicit cross-block overlap) AND
//     explicit 2-deep pipeline per block. BK=32 aligns with packed 8KB
//     weight tiles. reads/MFMA = 0.375. (row>>1)&3 XOR swizzle (64B rows)
//     pre-applied on global src, re-applied on ds_read.
//     One barrier + one vmcnt per K-tile; stage issued a full tile early.

#define Hdim 1024
#define Fdim 4096
#define NE 8
#define NT 8192
#define NPAIR 16384
#define OUT0 (NT * Hdim)   // 8388608 floats, then router_logits [NT,8]

typedef unsigned short u16;
typedef __bf16 bf16x8 __attribute__((ext_vector_type(8)));
typedef unsigned short u16x8 __attribute__((ext_vector_type(8)));
typedef float f32x4 __attribute__((ext_vector_type(4)));

// ---- workspace layout (bytes) ----
#define WS_HDR      0ull
#define WS_TOKTOP   4096ull
#define WS_TOKW     69632ull
#define WS_ROWTOK   135168ull
#define WS_ROWW     200704ull
#define WS_XG       266240ull          // bf16 [16384][1024]
#define WS_WG       33820672ull        // packed bf16 [8][32][32][128][32]
#define WS_WU       100929536ull
#define WS_WD       168038400ull       // packed bf16 [8][8][128][128][32]
#define WS_ACT      235147264ull       // bf16 [16384][4096]
#define WS_NEEDED   369364992ull

// hdr int indices
#define HDR_CNT 0
#define HDR_OFF 8
#define HDR_CUR 16
#define HDR_TOTALM 24
#define HDR_BEXP 32      // 160 slots
#define HDR_BSTART 192
#define HDR_BCNT 352

__device__ __forceinline__ u16 f2bf(float f) {
  union { float f; unsigned int u; } v; v.f = f;
  unsigned int u = v.u;
  u += 0x7fffu + ((u >> 16) & 1u);   // round-to-nearest-even
  return (u16)(u >> 16);
}

// async global->LDS, 16B per lane. lds base must be wave-uniform; HW adds lane*16.
__device__ __forceinline__ void gl2lds16(const void* g, void* l) {
  __builtin_amdgcn_global_load_lds(
      (__attribute__((address_space(1))) void*)(uintptr_t)g,
      (__attribute__((address_space(3))) void*)(uint32_t)(uintptr_t)l,
      16, 0, 0);
}

__global__ void k_sentinel(float* out) { out[0] = 3.0e8f; }

// ---- pack: fp32 [K][N] -> bf16 tiles [nb][kb][128][32], contiguous 8KB each ----
__global__ void k_pack(const float* __restrict__ wgp, const float* __restrict__ wup,
                       const float* __restrict__ wdp, u16* __restrict__ PG,
                       u16* __restrict__ PU, u16* __restrict__ PD) {
  __shared__ float lds[32 * 129];
  int tile = blockIdx.x;
  int tensor = tile >> 13;     // 8192 tiles per tensor
  int rem = tile & 8191;
  const float* src; u16* dst; int rowStride;
  int e = rem >> 10, r2 = rem & 1023;
  if (tensor == 0) {
    int nb = r2 >> 5, kb = r2 & 31;
    src = wgp + ((size_t)e * 1024 + kb * 32) * 4096 + nb * 128;
    rowStride = 4096; dst = PG + (size_t)rem * 4096;
  } else if (tensor == 1) {
    int nb = r2 >> 5, kb = r2 & 31;
    src = wup + ((size_t)e * 1024 + kb * 32) * 4096 + nb * 128;
    rowStride = 4096; dst = PU + (size_t)rem * 4096;
  } else {
    int nb = r2 >> 7, kb = r2 & 127;
    src = wdp + ((size_t)e * 4096 + kb * 32) * 1024 + nb * 128;
    rowStride = 1024; dst = PD + (size_t)rem * 4096;
  }
  int tid = threadIdx.x;
  for (int h = 0; h < 4; ++h) {
    int c = tid + h * 256;          // 1024 float4 chunks
    int k = c >> 5, n = (c & 31) * 4;
    f32x4 v = *(const f32x4*)(src + (size_t)k * rowStride + n);
    lds[k * 129 + n + 0] = v[0];
    lds[k * 129 + n + 1] = v[1];
    lds[k * 129 + n + 2] = v[2];
    lds[k * 129 + n + 3] = v[3];
  }
  __syncthreads();
  for (int h = 0; h < 2; ++h) {
    int c = tid + h * 256;          // 512 16B chunks of dst
    int ni = c >> 2, ki0 = (c & 3) * 8;
    u16x8 o;
#pragma unroll
    for (int j = 0; j < 8; ++j) o[j] = f2bf(lds[(ki0 + j) * 129 + ni]);
    *(u16x8*)(dst + c * 8) = o;
  }
}

// ---- router: logits, softmax, top-2, counts ----
__global__ void k_router(const float* __restrict__ x, const float* __restrict__ wg,
                         float* __restrict__ logits, int* __restrict__ hdr,
                         int* __restrict__ tokTop, float* __restrict__ tokW) {
  int t = blockIdx.x;
  int lane = threadIdx.x;   // 64 threads
  float acc[NE] = {0.f, 0.f, 0.f, 0.f, 0.f, 0.f, 0.f, 0.f};
  const float* xr = x + (size_t)t * Hdim + lane * 16;
#pragma unroll
  for (int j4 = 0; j4 < 4; ++j4) {
    f32x4 xv = *(const f32x4*)(xr + j4 * 4);
    int k0 = lane * 16 + j4 * 4;
#pragma unroll
    for (int kk = 0; kk < 4; ++kk) {
      f32x4 w0 = *(const f32x4*)(wg + (size_t)(k0 + kk) * 8);
      f32x4 w1 = *(const f32x4*)(wg + (size_t)(k0 + kk) * 8 + 4);
      float xs = xv[kk];
      acc[0] += xs * w0[0]; acc[1] += xs * w0[1]; acc[2] += xs * w0[2]; acc[3] += xs * w0[3];
      acc[4] += xs * w1[0]; acc[5] += xs * w1[1]; acc[6] += xs * w1[2]; acc[7] += xs * w1[3];
    }
  }
#pragma unroll
  for (int off = 32; off > 0; off >>= 1)
#pragma unroll
    for (int e = 0; e < NE; ++e) acc[e] += __shfl_xor(acc[e], off, 64);
  if (lane < NE) logits[(size_t)t * NE + lane] = acc[lane];
  if (lane == 0) {
    float m = acc[0];
#pragma unroll
    for (int e = 1; e < NE; ++e) m = fmaxf(m, acc[e]);
    float p[NE];
#pragma unroll
    for (int e = 0; e < NE; ++e) p[e] = expf(acc[e] - m);
    int i1 = 0; float p1 = p[0];
#pragma unroll
    for (int e = 1; e < NE; ++e) if (p[e] > p1) { p1 = p[e]; i1 = e; }
    int i2 = -1; float p2 = -1.f;
#pragma unroll
    for (int e = 0; e < NE; ++e) if (e != i1 && p[e] > p2) { p2 = p[e]; i2 = e; }
    float s = p1 + p2;
    tokTop[t * 2] = i1; tokTop[t * 2 + 1] = i2;
    tokW[t * 2] = p1 / s; tokW[t * 2 + 1] = p2 / s;
    atomicAdd(&hdr[HDR_CNT + i1], 1);
    atomicAdd(&hdr[HDR_CNT + i2], 1);
  }
}

// ---- scan: expert offsets + M-block map (<=136 blocks) ----
__global__ void k_scan(int* hdr) {
  if (threadIdx.x != 0 || blockIdx.x != 0) return;
  int cum = 0, mb = 0;
  for (int e = 0; e < NE; ++e) {
    hdr[HDR_OFF + e] = cum;
    int c = hdr[HDR_CNT + e];
    int nb = (c + 127) >> 7;
    for (int b = 0; b < nb; ++b) {
      hdr[HDR_BEXP + mb] = e;
      hdr[HDR_BSTART + mb] = cum + b * 128;
      int rc = c - b * 128; if (rc > 128) rc = 128;
      hdr[HDR_BCNT + mb] = rc;
      ++mb;
    }
    cum += c;
  }
  hdr[HDR_TOTALM] = mb;
}

// ---- place pairs into compact per-expert segments ----
__global__ void k_place(int* __restrict__ hdr, const int* __restrict__ tokTop,
                        const float* __restrict__ tokW, int* __restrict__ rowTok,
                        float* __restrict__ rowW) {
  int t = blockIdx.x * 256 + threadIdx.x;
  if (t >= NT) return;
#pragma unroll
  for (int k = 0; k < 2; ++k) {
    int e = tokTop[t * 2 + k];
    int pos = hdr[HDR_OFF + e] + atomicAdd(&hdr[HDR_CUR + e], 1);
    rowTok[pos] = t;
    rowW[pos] = tokW[t * 2 + k];
  }
}

// ---- gather x rows -> bf16 xg[pair][1024] ----
__global__ void k_gather(const float* __restrict__ x, const int* __restrict__ rowTok,
                         u16* __restrict__ xg) {
  int wid = threadIdx.x >> 6, lane = threadIdx.x & 63;
  int p = blockIdx.x * 4 + wid;
  int tok = rowTok[p];
  const float* src = x + (size_t)tok * Hdim;
  u16* dst = xg + (size_t)p * Hdim;
#pragma unroll
  for (int it = 0; it < 2; ++it) {
    int b = it * 512 + lane * 8;
    f32x4 a = *(const f32x4*)(src + b);
    f32x4 c = *(const f32x4*)(src + b + 4);
    u16x8 o;
    o[0] = f2bf(a[0]); o[1] = f2bf(a[1]); o[2] = f2bf(a[2]); o[3] = f2bf(a[3]);
    o[4] = f2bf(c[0]); o[5] = f2bf(c[1]); o[6] = f2bf(c[2]); o[7] = f2bf(c[3]);
    *(u16x8*)(dst + b) = o;
  }
}

// ---- GEMM1: [rows,1024]x[1024,128] dual (gate & up), fused SiLU*up -> act ----
// 256 thr / 4 waves (2M x 2N). Block tile 128(M) x 128(F) dual, BK=32 (=packed kb).
// Per-wave 64x64 dual: i4 x j4 x 2 = 32 MFMA / 12 ds_read per tile (0.375).
// LDS 2 x 24KB (A 8K | G 8K | U 8K) -> 2 blocks/CU. One barrier + one
// vmcnt(0) per tile; stage(t+1) issued right after, so its loads fly across
// the next barrier and the wait costs ~0.
#define NT1 32
__global__ __launch_bounds__(256, 2) void k_gemm1(
    const u16* __restrict__ xg, const u16* __restrict__ PG, const u16* __restrict__ PU,
    const int* __restrict__ hdr, u16* __restrict__ act) {
  extern __shared__ char ldsDyn[];
  int m = blockIdx.y;
  if (m >= hdr[HDR_TOTALM]) return;
  int e = hdr[HDR_BEXP + m], rowStart = hdr[HDR_BSTART + m], rowCnt = hdr[HDR_BCNT + m];
  int nb = blockIdx.x;                       // 0..31 over F in 128-col tiles
  int tid = threadIdx.x, lane = tid & 63, wid = tid >> 6;
  int wm = (wid & 1) * 64, wn = (wid >> 1) * 64;
  int rA = lane & 15, q = lane >> 4;

  // staging sources: per-lane PRE-SWIZZLED global addr; LDS dest linear.
  // 64B rows (32 bf16): slot s (of 4 x 16B) holds logical chunk s^((row>>1)&3).
  const u16* srcA[2];
  const u16* srcG[2];
  const u16* srcU[2];
  size_t wbase = ((size_t)e * 1024 + (size_t)nb * 32) * 4096;
#pragma unroll
  for (int h = 0; h < 2; ++h) {
    int c = h * 256 + tid;           // 0..511
    int row = c >> 2, s = c & 3;
    int k0 = (s ^ ((row >> 1) & 3)) * 8;
    int p = rowStart + row; if (p > NPAIR - 1) p = NPAIR - 1;
    srcA[h] = xg + (size_t)p * 1024 + k0;
    srcG[h] = PG + wbase + row * 32 + k0;    // row==n for weights
    srcU[h] = PU + wbase + row * 32 + k0;
  }

  // read-side offsets (same XOR)
  int kx = (q ^ ((rA >> 1) & 3)) << 4;       // byte offset within 64B row
  int arb[4], brb[4];
#pragma unroll
  for (int i = 0; i < 4; ++i) arb[i] = (wm + i * 16 + rA) * 64;
#pragma unroll
  for (int j = 0; j < 4; ++j) brb[j] = (wn + j * 16 + rA) * 64;

  f32x4 ag[4][4] = {};
  f32x4 au[4][4] = {};

  auto stage = [&](int tt) {                 // 6 gl2lds per wave
    char* b = ldsDyn + (size_t)(tt & 1) * 24576;
    size_t aoff = (size_t)tt * 32;
    size_t woff = (size_t)tt * 4096;
#pragma unroll
    for (int h = 0; h < 2; ++h) {
      gl2lds16(srcA[h] + aoff, b + h * 4096 + wid * 1024);
      gl2lds16(srcG[h] + woff, b + 8192 + h * 4096 + wid * 1024);
      gl2lds16(srcU[h] + woff, b + 16384 + h * 4096 + wid * 1024);
    }
  };

  stage(0);
  for (int t = 0; t < NT1; ++t) {
    asm volatile("s_waitcnt vmcnt(0)" ::: "memory");
    __builtin_amdgcn_s_barrier();
    asm volatile("" ::: "memory");
    if (t + 1 < NT1) stage(t + 1);
    const char* b = ldsDyn + (size_t)(t & 1) * 24576;
    bf16x8 a[4], g[4], u[4];
#pragma unroll
    for (int i = 0; i < 4; ++i)
      a[i] = __builtin_bit_cast(bf16x8, *(const u16x8*)(b + arb[i] + kx));
#pragma unroll
    for (int j = 0; j < 4; ++j) {
      g[j] = __builtin_bit_cast(bf16x8, *(const u16x8*)(b + 8192 + brb[j] + kx));
      u[j] = __builtin_bit_cast(bf16x8, *(const u16x8*)(b + 16384 + brb[j] + kx));
    }
    __builtin_amdgcn_s_setprio(1);
#pragma unroll
    for (int i = 0; i < 4; ++i)
#pragma unroll
      for (int j = 0; j < 4; ++j) {
        ag[i][j] = __builtin_amdgcn_mfma_f32_16x16x32_bf16(a[i], g[j], ag[i][j], 0, 0, 0);
        au[i][j] = __builtin_amdgcn_mfma_f32_16x16x32_bf16(a[i], u[j], au[i][j], 0, 0, 0);
      }
    __builtin_amdgcn_s_setprio(0);
  }
  // epilogue: h = silu(g)*u -> bf16 act[pair][F]
#pragma unroll
  for (int i = 0; i < 4; ++i)
#pragma unroll
    for (int r = 0; r < 4; ++r) {
      int row = wm + i * 16 + q * 4 + r;
      if (row < rowCnt) {
        size_t base = (size_t)(rowStart + row) * 4096 + nb * 128 + wn;
#pragma unroll
        for (int j = 0; j < 4; ++j) {
          float gv = ag[i][j][r], uv = au[i][j][r];
          float hv = (gv / (1.f + expf(-gv))) * uv;
          act[base + j * 16 + rA] = f2bf(hv);
        }
      }
    }
}

// ---- GEMM2: [rows,4096]x[4096,256] -> weighted atomic scatter into out ----
// 256 thr / 4 waves (1M x 4N). Block tile 128(M) x 256(H), BK=32, 128 tiles.
// Per-wave 128x64: i8 x j4 = 32 MFMA / 12 ds_read (0.375). LDS 2 x 24KB
// (A 8K | B 16K). Grid 4 x 136 = 544 blocks ~ one GPU round at 2/CU.
#define NT2 128
__global__ __launch_bounds__(256, 2) void k_gemm2(
    const u16* __restrict__ act, const u16* __restrict__ PD,
    const int* __restrict__ hdr, const int* __restrict__ rowTok,
    const float* __restrict__ rowW, float* __restrict__ out) {
  extern __shared__ char ldsDyn[];
  int m = blockIdx.y;
  if (m >= hdr[HDR_TOTALM]) return;
  int e = hdr[HDR_BEXP + m], rowStart = hdr[HDR_BSTART + m], rowCnt = hdr[HDR_BCNT + m];
  int nb = blockIdx.x;                      // 0..3 over H in 256-col tiles
  int tid = threadIdx.x, lane = tid & 63, wid = tid >> 6;
  int wn = wid * 64;
  int rA = lane & 15, q = lane >> 4;

  const u16* srcA[2];
  const u16* srcB[4];
#pragma unroll
  for (int h = 0; h < 2; ++h) {
    int c = h * 256 + tid;                  // 0..511
    int row = c >> 2, s = c & 3;
    int k0 = (s ^ ((row >> 1) & 3)) * 8;
    int p = rowStart + row; if (p > NPAIR - 1) p = NPAIR - 1;
    srcA[h] = act + (size_t)p * 4096 + k0;
  }
#pragma unroll
  for (int h = 0; h < 4; ++h) {
    int c = h * 256 + tid;                  // 0..1023
    int n = c >> 2, s = c & 3;
    int k0 = (s ^ ((n >> 1) & 3)) * 8;
    srcB[h] = PD + ((size_t)((e * 8 + nb * 2 + (n >> 7)) * 128)) * 4096
                 + (size_t)(n & 127) * 32 + k0;
  }

  int kx = (q ^ ((rA >> 1) & 3)) << 4;
  int arb[8], brb[4];
#pragma unroll
  for (int i = 0; i < 8; ++i) arb[i] = (i * 16 + rA) * 64;
#pragma unroll
  for (int j = 0; j < 4; ++j) brb[j] = (wn + j * 16 + rA) * 64;

  f32x4 acc[8][4] = {};

  auto stage = [&](int tt) {                // 6 gl2lds per wave
    char* b = ldsDyn + (size_t)(tt & 1) * 24576;
    size_t aoff = (size_t)tt * 32;
    size_t woff = (size_t)tt * 4096;
#pragma unroll
    for (int h = 0; h < 2; ++h)
      gl2lds16(srcA[h] + aoff, b + h * 4096 + wid * 1024);
#pragma unroll
    for (int h = 0; h < 4; ++h)
      gl2lds16(srcB[h] + woff, b + 8192 + h * 4096 + wid * 1024);
  };

  stage(0);
  for (int t = 0; t < NT2; ++t) {
    asm volatile("s_waitcnt vmcnt(0)" ::: "memory");
    __builtin_amdgcn_s_barrier();
    asm volatile("" ::: "memory");
    if (t + 1 < NT2) stage(t + 1);
    const char* b = ldsDyn + (size_t)(t & 1) * 24576;
    bf16x8 a[8], bb[4];
#pragma unroll
    for (int i = 0; i < 8; ++i)
      a[i] = __builtin_bit_cast(bf16x8, *(const u16x8*)(b + arb[i] + kx));
#pragma unroll
    for (int j = 0; j < 4; ++j)
      bb[j] = __builtin_bit_cast(bf16x8, *(const u16x8*)(b + 8192 + brb[j] + kx));
    __builtin_amdgcn_s_setprio(1);
#pragma unroll
    for (int i = 0; i < 8; ++i)
#pragma unroll
      for (int j = 0; j < 4; ++j)
        acc[i][j] = __builtin_amdgcn_mfma_f32_16x16x32_bf16(a[i], bb[j], acc[i][j], 0, 0, 0);
    __builtin_amdgcn_s_setprio(0);
  }
#pragma unroll
  for (int i = 0; i < 8; ++i)
#pragma unroll
    for (int r = 0; r < 4; ++r) {
      int row = i * 16 + q * 4 + r;
      if (row < rowCnt) {
        int p = rowStart + row;
        int tok = rowTok[p];
        float w = rowW[p];
        size_t base = (size_t)tok * Hdim + nb * 256 + wn;
#pragma unroll
        for (int j = 0; j < 4; ++j)
          atomicAdd(&out[base + j * 16 + rA], w * acc[i][j][r]);
      }
    }
}

extern "C" void kernel_launch(void* const* d_in, const int* in_sizes, int n_in,
                              void* d_out, int out_size, void* d_ws, size_t ws_size,
                              hipStream_t stream) {
  const float* x   = (const float*)d_in[0];
  const float* wg  = (const float*)d_in[1];
  const float* wgp = (const float*)d_in[2];
  const float* wup = (const float*)d_in[3];
  const float* wdp = (const float*)d_in[4];
  float* out = (float*)d_out;

  if (ws_size < WS_NEEDED) { k_sentinel<<<1, 1, 0, stream>>>(out); return; }

  static int attrDone = 0;
  if (!attrDone) {
    hipFuncSetAttribute((const void*)k_gemm1,
                        hipFuncAttributeMaxDynamicSharedMemorySize, 49152);
    hipFuncSetAttribute((const void*)k_gemm2,
                        hipFuncAttributeMaxDynamicSharedMemorySize, 49152);
    attrDone = 1;
  }

  char* ws = (char*)d_ws;
  int*   hdr    = (int*)(ws + WS_HDR);
  int*   tokTop = (int*)(ws + WS_TOKTOP);
  float* tokW   = (float*)(ws + WS_TOKW);
  int*   rowTok = (int*)(ws + WS_ROWTOK);
  float* rowW   = (float*)(ws + WS_ROWW);
  u16*   xg     = (u16*)(ws + WS_XG);
  u16*   PG     = (u16*)(ws + WS_WG);
  u16*   PU     = (u16*)(ws + WS_WU);
  u16*   PD     = (u16*)(ws + WS_WD);
  u16*   act    = (u16*)(ws + WS_ACT);

  hipMemsetAsync(hdr, 0, 4096, stream);
  hipMemsetAsync(out, 0, (size_t)OUT0 * sizeof(float), stream);

  k_pack<<<24576, 256, 0, stream>>>(wgp, wup, wdp, PG, PU, PD);
  k_router<<<NT, 64, 0, stream>>>(x, wg, out + OUT0, hdr, tokTop, tokW);
  k_scan<<<1, 1, 0, stream>>>(hdr);
  k_place<<<32, 256, 0, stream>>>(hdr, tokTop, tokW, rowTok, rowW);
  k_gather<<<4096, 256, 0, stream>>>(x, rowTok, xg);
  k_gemm1<<<dim3(32, 136), 256, 49152, stream>>>(xg, PG, PU, hdr, act);
  k_gemm2<<<dim3(4, 136), 256, 49152, stream>>>(act, PD, hdr, rowTok, rowW, out);
}

// Round 4
// 1193.939 us; speedup vs baseline: 1.0969x; 1.0683x over previous
//
#include <hip/hip_runtime.h>
#include <stdint.h>

// MoE top-2 SwiGLU FFN, MI355X. fp32 in/out, bf16 MFMA compute.
// B=4 S=2048 H=1024 F=4096 E=8 K=2 -> T=8192 tokens, 16384 pairs.
// R5: R4 + pipeline depth 2->3 with COUNTED vmcnt(6) (never 0 in main loop).
//     Wait at tile t is for loads issued 2 tiles ago -> ~600cy window covers
//     L2 (~200cy) and most HBM (~900cy) latency. Bank conflicts already 0
//     (verified R4). 4-wave blocks, 2 blocks/CU, BK=32, reads/MFMA = 0.375.

#define Hdim 1024
#define Fdim 4096
#define NE 8
#define NT 8192
#define NPAIR 16384
#define OUT0 (NT * Hdim)   // 8388608 floats, then router_logits [NT,8]

typedef unsigned short u16;
typedef __bf16 bf16x8 __attribute__((ext_vector_type(8)));
typedef unsigned short u16x8 __attribute__((ext_vector_type(8)));
typedef float f32x4 __attribute__((ext_vector_type(4)));

// ---- workspace layout (bytes) ----
#define WS_HDR      0ull
#define WS_TOKTOP   4096ull
#define WS_TOKW     69632ull
#define WS_ROWTOK   135168ull
#define WS_ROWW     200704ull
#define WS_XG       266240ull          // bf16 [16384][1024]
#define WS_WG       33820672ull        // packed bf16 [8][32][32][128][32]
#define WS_WU       100929536ull
#define WS_WD       168038400ull       // packed bf16 [8][8][128][128][32]
#define WS_ACT      235147264ull       // bf16 [16384][4096]
#define WS_NEEDED   369364992ull

// hdr int indices
#define HDR_CNT 0
#define HDR_OFF 8
#define HDR_CUR 16
#define HDR_TOTALM 24
#define HDR_BEXP 32      // 160 slots
#define HDR_BSTART 192
#define HDR_BCNT 352

__device__ __forceinline__ u16 f2bf(float f) {
  union { float f; unsigned int u; } v; v.f = f;
  unsigned int u = v.u;
  u += 0x7fffu + ((u >> 16) & 1u);   // round-to-nearest-even
  return (u16)(u >> 16);
}

// async global->LDS, 16B per lane. lds base must be wave-uniform; HW adds lane*16.
__device__ __forceinline__ void gl2lds16(const void* g, void* l) {
  __builtin_amdgcn_global_load_lds(
      (__attribute__((address_space(1))) void*)(uintptr_t)g,
      (__attribute__((address_space(3))) void*)(uint32_t)(uintptr_t)l,
      16, 0, 0);
}

__global__ void k_sentinel(float* out) { out[0] = 3.0e8f; }

// ---- pack: fp32 [K][N] -> bf16 tiles [nb][kb][128][32], contiguous 8KB each ----
__global__ void k_pack(const float* __restrict__ wgp, const float* __restrict__ wup,
                       const float* __restrict__ wdp, u16* __restrict__ PG,
                       u16* __restrict__ PU, u16* __restrict__ PD) {
  __shared__ float lds[32 * 129];
  int tile = blockIdx.x;
  int tensor = tile >> 13;     // 8192 tiles per tensor
  int rem = tile & 8191;
  const float* src; u16* dst; int rowStride;
  int e = rem >> 10, r2 = rem & 1023;
  if (tensor == 0) {
    int nb = r2 >> 5, kb = r2 & 31;
    src = wgp + ((size_t)e * 1024 + kb * 32) * 4096 + nb * 128;
    rowStride = 4096; dst = PG + (size_t)rem * 4096;
  } else if (tensor == 1) {
    int nb = r2 >> 5, kb = r2 & 31;
    src = wup + ((size_t)e * 1024 + kb * 32) * 4096 + nb * 128;
    rowStride = 4096; dst = PU + (size_t)rem * 4096;
  } else {
    int nb = r2 >> 7, kb = r2 & 127;
    src = wdp + ((size_t)e * 4096 + kb * 32) * 1024 + nb * 128;
    rowStride = 1024; dst = PD + (size_t)rem * 4096;
  }
  int tid = threadIdx.x;
  for (int h = 0; h < 4; ++h) {
    int c = tid + h * 256;          // 1024 float4 chunks
    int k = c >> 5, n = (c & 31) * 4;
    f32x4 v = *(const f32x4*)(src + (size_t)k * rowStride + n);
    lds[k * 129 + n + 0] = v[0];
    lds[k * 129 + n + 1] = v[1];
    lds[k * 129 + n + 2] = v[2];
    lds[k * 129 + n + 3] = v[3];
  }
  __syncthreads();
  for (int h = 0; h < 2; ++h) {
    int c = tid + h * 256;          // 512 16B chunks of dst
    int ni = c >> 2, ki0 = (c & 3) * 8;
    u16x8 o;
#pragma unroll
    for (int j = 0; j < 8; ++j) o[j] = f2bf(lds[(ki0 + j) * 129 + ni]);
    *(u16x8*)(dst + c * 8) = o;
  }
}

// ---- router: logits, softmax, top-2, counts ----
__global__ void k_router(const float* __restrict__ x, const float* __restrict__ wg,
                         float* __restrict__ logits, int* __restrict__ hdr,
                         int* __restrict__ tokTop, float* __restrict__ tokW) {
  int t = blockIdx.x;
  int lane = threadIdx.x;   // 64 threads
  float acc[NE] = {0.f, 0.f, 0.f, 0.f, 0.f, 0.f, 0.f, 0.f};
  const float* xr = x + (size_t)t * Hdim + lane * 16;
#pragma unroll
  for (int j4 = 0; j4 < 4; ++j4) {
    f32x4 xv = *(const f32x4*)(xr + j4 * 4);
    int k0 = lane * 16 + j4 * 4;
#pragma unroll
    for (int kk = 0; kk < 4; ++kk) {
      f32x4 w0 = *(const f32x4*)(wg + (size_t)(k0 + kk) * 8);
      f32x4 w1 = *(const f32x4*)(wg + (size_t)(k0 + kk) * 8 + 4);
      float xs = xv[kk];
      acc[0] += xs * w0[0]; acc[1] += xs * w0[1]; acc[2] += xs * w0[2]; acc[3] += xs * w0[3];
      acc[4] += xs * w1[0]; acc[5] += xs * w1[1]; acc[6] += xs * w1[2]; acc[7] += xs * w1[3];
    }
  }
#pragma unroll
  for (int off = 32; off > 0; off >>= 1)
#pragma unroll
    for (int e = 0; e < NE; ++e) acc[e] += __shfl_xor(acc[e], off, 64);
  if (lane < NE) logits[(size_t)t * NE + lane] = acc[lane];
  if (lane == 0) {
    float m = acc[0];
#pragma unroll
    for (int e = 1; e < NE; ++e) m = fmaxf(m, acc[e]);
    float p[NE];
#pragma unroll
    for (int e = 0; e < NE; ++e) p[e] = expf(acc[e] - m);
    int i1 = 0; float p1 = p[0];
#pragma unroll
    for (int e = 1; e < NE; ++e) if (p[e] > p1) { p1 = p[e]; i1 = e; }
    int i2 = -1; float p2 = -1.f;
#pragma unroll
    for (int e = 0; e < NE; ++e) if (e != i1 && p[e] > p2) { p2 = p[e]; i2 = e; }
    float s = p1 + p2;
    tokTop[t * 2] = i1; tokTop[t * 2 + 1] = i2;
    tokW[t * 2] = p1 / s; tokW[t * 2 + 1] = p2 / s;
    atomicAdd(&hdr[HDR_CNT + i1], 1);
    atomicAdd(&hdr[HDR_CNT + i2], 1);
  }
}

// ---- scan: expert offsets + M-block map (<=136 blocks) ----
__global__ void k_scan(int* hdr) {
  if (threadIdx.x != 0 || blockIdx.x != 0) return;
  int cum = 0, mb = 0;
  for (int e = 0; e < NE; ++e) {
    hdr[HDR_OFF + e] = cum;
    int c = hdr[HDR_CNT + e];
    int nb = (c + 127) >> 7;
    for (int b = 0; b < nb; ++b) {
      hdr[HDR_BEXP + mb] = e;
      hdr[HDR_BSTART + mb] = cum + b * 128;
      int rc = c - b * 128; if (rc > 128) rc = 128;
      hdr[HDR_BCNT + mb] = rc;
      ++mb;
    }
    cum += c;
  }
  hdr[HDR_TOTALM] = mb;
}

// ---- place pairs into compact per-expert segments ----
__global__ void k_place(int* __restrict__ hdr, const int* __restrict__ tokTop,
                        const float* __restrict__ tokW, int* __restrict__ rowTok,
                        float* __restrict__ rowW) {
  int t = blockIdx.x * 256 + threadIdx.x;
  if (t >= NT) return;
#pragma unroll
  for (int k = 0; k < 2; ++k) {
    int e = tokTop[t * 2 + k];
    int pos = hdr[HDR_OFF + e] + atomicAdd(&hdr[HDR_CUR + e], 1);
    rowTok[pos] = t;
    rowW[pos] = tokW[t * 2 + k];
  }
}

// ---- gather x rows -> bf16 xg[pair][1024] ----
__global__ void k_gather(const float* __restrict__ x, const int* __restrict__ rowTok,
                         u16* __restrict__ xg) {
  int wid = threadIdx.x >> 6, lane = threadIdx.x & 63;
  int p = blockIdx.x * 4 + wid;
  int tok = rowTok[p];
  const float* src = x + (size_t)tok * Hdim;
  u16* dst = xg + (size_t)p * Hdim;
#pragma unroll
  for (int it = 0; it < 2; ++it) {
    int b = it * 512 + lane * 8;
    f32x4 a = *(const f32x4*)(src + b);
    f32x4 c = *(const f32x4*)(src + b + 4);
    u16x8 o;
    o[0] = f2bf(a[0]); o[1] = f2bf(a[1]); o[2] = f2bf(a[2]); o[3] = f2bf(a[3]);
    o[4] = f2bf(c[0]); o[5] = f2bf(c[1]); o[6] = f2bf(c[2]); o[7] = f2bf(c[3]);
    *(u16x8*)(dst + b) = o;
  }
}

// ---- GEMM1: [rows,1024]x[1024,128] dual (gate & up), fused SiLU*up -> act ----
// 256 thr / 4 waves (2M x 2N). Block tile 128(M) x 128(F) dual, BK=32.
// Per-wave 64x64 dual: 32 MFMA / 12 ds_read per tile (0.375).
// LDS 3 x 24KB (A 8K | G 8K | U 8K) -> 2 blocks/CU. Counted vmcnt(6):
// wait for tile t (issued at t-2) while tile t+1's 6 loads stay in flight.
#define NT1 32
__global__ __launch_bounds__(256, 2) void k_gemm1(
    const u16* __restrict__ xg, const u16* __restrict__ PG, const u16* __restrict__ PU,
    const int* __restrict__ hdr, u16* __restrict__ act) {
  extern __shared__ char ldsDyn[];
  int m = blockIdx.y;
  if (m >= hdr[HDR_TOTALM]) return;
  int e = hdr[HDR_BEXP + m], rowStart = hdr[HDR_BSTART + m], rowCnt = hdr[HDR_BCNT + m];
  int nb = blockIdx.x;                       // 0..31 over F in 128-col tiles
  int tid = threadIdx.x, lane = tid & 63, wid = tid >> 6;
  int wm = (wid & 1) * 64, wn = (wid >> 1) * 64;
  int rA = lane & 15, q = lane >> 4;

  // staging sources: per-lane PRE-SWIZZLED global addr; LDS dest linear.
  // 64B rows (32 bf16): slot s (of 4 x 16B) holds logical chunk s^((row>>1)&3).
  const u16* srcA[2];
  const u16* srcG[2];
  const u16* srcU[2];
  size_t wbase = ((size_t)e * 1024 + (size_t)nb * 32) * 4096;
#pragma unroll
  for (int h = 0; h < 2; ++h) {
    int c = h * 256 + tid;           // 0..511
    int row = c >> 2, s = c & 3;
    int k0 = (s ^ ((row >> 1) & 3)) * 8;
    int p = rowStart + row; if (p > NPAIR - 1) p = NPAIR - 1;
    srcA[h] = xg + (size_t)p * 1024 + k0;
    srcG[h] = PG + wbase + row * 32 + k0;    // row==n for weights
    srcU[h] = PU + wbase + row * 32 + k0;
  }

  // read-side offsets (same XOR)
  int kx = (q ^ ((rA >> 1) & 3)) << 4;       // byte offset within 64B row
  int arb[4], brb[4];
#pragma unroll
  for (int i = 0; i < 4; ++i) arb[i] = (wm + i * 16 + rA) * 64;
#pragma unroll
  for (int j = 0; j < 4; ++j) brb[j] = (wn + j * 16 + rA) * 64;

  f32x4 ag[4][4] = {};
  f32x4 au[4][4] = {};

  auto stage = [&](int tt, char* b) {        // 6 gl2lds per wave
    size_t aoff = (size_t)tt * 32;
    size_t woff = (size_t)tt * 4096;
#pragma unroll
    for (int h = 0; h < 2; ++h) {
      gl2lds16(srcA[h] + aoff, b + h * 4096 + wid * 1024);
      gl2lds16(srcG[h] + woff, b + 8192 + h * 4096 + wid * 1024);
      gl2lds16(srcU[h] + woff, b + 16384 + h * 4096 + wid * 1024);
    }
  };

  stage(0, ldsDyn);
  stage(1, ldsDyn + 24576);
  int cur = 0;
  for (int t = 0; t < NT1; ++t) {
    // counted wait: tile t resident; tile t+1's 6 loads stay in flight
    if (t < NT1 - 1) asm volatile("s_waitcnt vmcnt(6)" ::: "memory");
    else             asm volatile("s_waitcnt vmcnt(0)" ::: "memory");
    __builtin_amdgcn_s_barrier();
    asm volatile("" ::: "memory");
    if (t + 2 < NT1) {
      int s2 = cur + 2; if (s2 >= 3) s2 -= 3;
      stage(t + 2, ldsDyn + (size_t)s2 * 24576);
    }
    const char* b = ldsDyn + (size_t)cur * 24576;
    bf16x8 a[4], g[4], u[4];
#pragma unroll
    for (int i = 0; i < 4; ++i)
      a[i] = __builtin_bit_cast(bf16x8, *(const u16x8*)(b + arb[i] + kx));
#pragma unroll
    for (int j = 0; j < 4; ++j) {
      g[j] = __builtin_bit_cast(bf16x8, *(const u16x8*)(b + 8192 + brb[j] + kx));
      u[j] = __builtin_bit_cast(bf16x8, *(const u16x8*)(b + 16384 + brb[j] + kx));
    }
    __builtin_amdgcn_s_setprio(1);
#pragma unroll
    for (int i = 0; i < 4; ++i)
#pragma unroll
      for (int j = 0; j < 4; ++j) {
        ag[i][j] = __builtin_amdgcn_mfma_f32_16x16x32_bf16(a[i], g[j], ag[i][j], 0, 0, 0);
        au[i][j] = __builtin_amdgcn_mfma_f32_16x16x32_bf16(a[i], u[j], au[i][j], 0, 0, 0);
      }
    __builtin_amdgcn_s_setprio(0);
    ++cur; if (cur == 3) cur = 0;
  }
  // epilogue: h = silu(g)*u -> bf16 act[pair][F]
#pragma unroll
  for (int i = 0; i < 4; ++i)
#pragma unroll
    for (int r = 0; r < 4; ++r) {
      int row = wm + i * 16 + q * 4 + r;
      if (row < rowCnt) {
        size_t base = (size_t)(rowStart + row) * 4096 + nb * 128 + wn;
#pragma unroll
        for (int j = 0; j < 4; ++j) {
          float gv = ag[i][j][r], uv = au[i][j][r];
          float hv = (gv / (1.f + expf(-gv))) * uv;
          act[base + j * 16 + rA] = f2bf(hv);
        }
      }
    }
}

// ---- GEMM2: [rows,4096]x[4096,256] -> weighted atomic scatter into out ----
// 256 thr / 4 waves (1M x 4N). Block tile 128(M) x 256(H), BK=32, 128 tiles.
// Per-wave 128x64: 32 MFMA / 12 ds_read (0.375). LDS 3 x 24KB (A 8K | B 16K).
// Counted vmcnt(6), stage t+2 while computing t.
#define NT2 128
__global__ __launch_bounds__(256, 2) void k_gemm2(
    const u16* __restrict__ act, const u16* __restrict__ PD,
    const int* __restrict__ hdr, const int* __restrict__ rowTok,
    const float* __restrict__ rowW, float* __restrict__ out) {
  extern __shared__ char ldsDyn[];
  int m = blockIdx.y;
  if (m >= hdr[HDR_TOTALM]) return;
  int e = hdr[HDR_BEXP + m], rowStart = hdr[HDR_BSTART + m], rowCnt = hdr[HDR_BCNT + m];
  int nb = blockIdx.x;                      // 0..3 over H in 256-col tiles
  int tid = threadIdx.x, lane = tid & 63, wid = tid >> 6;
  int wn = wid * 64;
  int rA = lane & 15, q = lane >> 4;

  const u16* srcA[2];
  const u16* srcB[4];
#pragma unroll
  for (int h = 0; h < 2; ++h) {
    int c = h * 256 + tid;                  // 0..511
    int row = c >> 2, s = c & 3;
    int k0 = (s ^ ((row >> 1) & 3)) * 8;
    int p = rowStart + row; if (p > NPAIR - 1) p = NPAIR - 1;
    srcA[h] = act + (size_t)p * 4096 + k0;
  }
#pragma unroll
  for (int h = 0; h < 4; ++h) {
    int c = h * 256 + tid;                  // 0..1023
    int n = c >> 2, s = c & 3;
    int k0 = (s ^ ((n >> 1) & 3)) * 8;
    srcB[h] = PD + ((size_t)((e * 8 + nb * 2 + (n >> 7)) * 128)) * 4096
                 + (size_t)(n & 127) * 32 + k0;
  }

  int kx = (q ^ ((rA >> 1) & 3)) << 4;
  int arb[8], brb[4];
#pragma unroll
  for (int i = 0; i < 8; ++i) arb[i] = (i * 16 + rA) * 64;
#pragma unroll
  for (int j = 0; j < 4; ++j) brb[j] = (wn + j * 16 + rA) * 64;

  f32x4 acc[8][4] = {};

  auto stage = [&](int tt, char* b) {       // 6 gl2lds per wave
    size_t aoff = (size_t)tt * 32;
    size_t woff = (size_t)tt * 4096;
#pragma unroll
    for (int h = 0; h < 2; ++h)
      gl2lds16(srcA[h] + aoff, b + h * 4096 + wid * 1024);
#pragma unroll
    for (int h = 0; h < 4; ++h)
      gl2lds16(srcB[h] + woff, b + 8192 + h * 4096 + wid * 1024);
  };

  stage(0, ldsDyn);
  stage(1, ldsDyn + 24576);
  int cur = 0;
  for (int t = 0; t < NT2; ++t) {
    if (t < NT2 - 1) asm volatile("s_waitcnt vmcnt(6)" ::: "memory");
    else             asm volatile("s_waitcnt vmcnt(0)" ::: "memory");
    __builtin_amdgcn_s_barrier();
    asm volatile("" ::: "memory");
    if (t + 2 < NT2) {
      int s2 = cur + 2; if (s2 >= 3) s2 -= 3;
      stage(t + 2, ldsDyn + (size_t)s2 * 24576);
    }
    const char* b = ldsDyn + (size_t)cur * 24576;
    bf16x8 a[8], bb[4];
#pragma unroll
    for (int i = 0; i < 8; ++i)
      a[i] = __builtin_bit_cast(bf16x8, *(const u16x8*)(b + arb[i] + kx));
#pragma unroll
    for (int j = 0; j < 4; ++j)
      bb[j] = __builtin_bit_cast(bf16x8, *(const u16x8*)(b + 8192 + brb[j] + kx));
    __builtin_amdgcn_s_setprio(1);
#pragma unroll
    for (int i = 0; i < 8; ++i)
#pragma unroll
      for (int j = 0; j < 4; ++j)
        acc[i][j] = __builtin_amdgcn_mfma_f32_16x16x32_bf16(a[i], bb[j], acc[i][j], 0, 0, 0);
    __builtin_amdgcn_s_setprio(0);
    ++cur; if (cur == 3) cur = 0;
  }
#pragma unroll
  for (int i = 0; i < 8; ++i)
#pragma unroll
    for (int r = 0; r < 4; ++r) {
      int row = i * 16 + q * 4 + r;
      if (row < rowCnt) {
        int p = rowStart + row;
        int tok = rowTok[p];
        float w = rowW[p];
        size_t base = (size_t)tok * Hdim + nb * 256 + wn;
#pragma unroll
        for (int j = 0; j < 4; ++j)
          atomicAdd(&out[base + j * 16 + rA], w * acc[i][j][r]);
      }
    }
}

extern "C" void kernel_launch(void* const* d_in, const int* in_sizes, int n_in,
                              void* d_out, int out_size, void* d_ws, size_t ws_size,
                              hipStream_t stream) {
  const float* x   = (const float*)d_in[0];
  const float* wg  = (const float*)d_in[1];
  const float* wgp = (const float*)d_in[2];
  const float* wup = (const float*)d_in[3];
  const float* wdp = (const float*)d_in[4];
  float* out = (float*)d_out;

  if (ws_size < WS_NEEDED) { k_sentinel<<<1, 1, 0, stream>>>(out); return; }

  static int attrDone = 0;
  if (!attrDone) {
    hipFuncSetAttribute((const void*)k_gemm1,
                        hipFuncAttributeMaxDynamicSharedMemorySize, 73728);
    hipFuncSetAttribute((const void*)k_gemm2,
                        hipFuncAttributeMaxDynamicSharedMemorySize, 73728);
    attrDone = 1;
  }

  char* ws = (char*)d_ws;
  int*   hdr    = (int*)(ws + WS_HDR);
  int*   tokTop = (int*)(ws + WS_TOKTOP);
  float* tokW   = (float*)(ws + WS_TOKW);
  int*   rowTok = (int*)(ws + WS_ROWTOK);
  float* rowW   = (float*)(ws + WS_ROWW);
  u16*   xg     = (u16*)(ws + WS_XG);
  u16*   PG     = (u16*)(ws + WS_WG);
  u16*   PU     = (u16*)(ws + WS_WU);
  u16*   PD     = (u16*)(ws + WS_WD);
  u16*   act    = (u16*)(ws + WS_ACT);

  hipMemsetAsync(hdr, 0, 4096, stream);
  hipMemsetAsync(out, 0, (size_t)OUT0 * sizeof(float), stream);

  k_pack<<<24576, 256, 0, stream>>>(wgp, wup, wdp, PG, PU, PD);
  k_router<<<NT, 64, 0, stream>>>(x, wg, out + OUT0, hdr, tokTop, tokW);
  k_scan<<<1, 1, 0, stream>>>(hdr);
  k_place<<<32, 256, 0, stream>>>(hdr, tokTop, tokW, rowTok, rowW);
  k_gather<<<4096, 256, 0, stream>>>(x, rowTok, xg);
  k_gemm1<<<dim3(32, 136), 256, 73728, stream>>>(xg, PG, PU, hdr, act);
  k_gemm2<<<dim3(4, 136), 256, 73728, stream>>>(act, PD, hdr, rowTok, rowW, out);
}